// Round 8
// baseline (445.068 us; speedup 1.0000x reference)
//
#include <hip/hip_runtime.h>
#include <math.h>

#define TOKENS 16384
#define HIDDEN 4096
#define NE 64
#define KSPLIT 4                     // PINNED: KSPLIT=8 changes the K-reduction
                                     // tree -> tie-flip on expert indices
                                     // (rounds 3-5, deterministic absmax 36).
#define KRANGE (HIDDEN / KSPLIT)     // 1024
#define KSTEPS (KRANGE / 32)         // 32 K32-steps per block
#define SSTEPS (KSTEPS / 4)          // 8 super-steps of 4 K-steps (512 B/row)

#define IDX_OFF 0
#define SC_OFF   (TOKENS * 2)
#define MASK_OFF (TOKENS * 4)
#define AUX_OFF  (MASK_OFF + TOKENS * 2 * NE)   // 2162688

#define KB_TOTAL (HIDDEN / 32)                  // 128 K32-blocks
#define WF_UINT4 (KB_TOTAL * 12 * 64)           // 98304 uint4 = 1.5 MB
#define P_FLOATS ((size_t)KSPLIT * TOKENS * NE) // 4.19M floats = 16.8 MB

typedef __attribute__((ext_vector_type(8))) short bf16x8;
typedef __attribute__((ext_vector_type(4))) float f32x4;
union U16x8 { uint4 u; bf16x8 v; unsigned w[4]; };

#define AS1 __attribute__((address_space(1)))
#define AS3 __attribute__((address_space(3)))

// Exact truncation split: v == hi + mid + lo bit-exactly (top 3 bf16 "digits").
__device__ inline void split3(float v, unsigned short& h, unsigned short& m,
                              unsigned short& l)
{
    const unsigned bu = __float_as_uint(v);
    const float fh = __uint_as_float(bu & 0xffff0000u);
    const float r  = v - fh;                       // exact
    const unsigned br = __float_as_uint(r);
    const float fm = __uint_as_float(br & 0xffff0000u);
    const float r2 = r - fm;                       // exact
    h = (unsigned short)(bu >> 16);
    m = (unsigned short)(br >> 16);
    l = (unsigned short)(__float_as_uint(r2) >> 16);
}

// Pair-packed split (bitwise identical to split3, fewer VALU ops):
// h/m/l each get [lo16 = digit(f0), hi16 = digit(f1)] via v_perm_b32.
__device__ inline void split2pk(float f0, float f1,
                                unsigned& h, unsigned& m, unsigned& l)
{
    const unsigned u0 = __float_as_uint(f0), u1 = __float_as_uint(f1);
    h = __builtin_amdgcn_perm(u1, u0, 0x07060302u);
    const float r0 = f0 - __uint_as_float(u0 & 0xffff0000u);   // exact
    const float r1 = f1 - __uint_as_float(u1 & 0xffff0000u);   // exact
    const unsigned v0 = __float_as_uint(r0), v1 = __float_as_uint(r1);
    m = __builtin_amdgcn_perm(v1, v0, 0x07060302u);
    const float s0 = r0 - __uint_as_float(v0 & 0xffff0000u);   // exact
    const float s1 = r1 - __uint_as_float(v1 & 0xffff0000u);   // exact
    l = __builtin_amdgcn_perm(__float_as_uint(s1), __float_as_uint(s0), 0x07060302u);
}

// Pre-split W into MFMA B-fragment order:
// frag(kb, s, nt): 64 lanes x 16 B; lane holds B[k=kb*32+(lane>>4)*8+j][n=nt*16+(lane&15)]
__global__ void prep_w(const float* __restrict__ Wg, uint4* __restrict__ Wf)
{
    const int kb = blockIdx.x;             // 0..127
    const int nt = threadIdx.x >> 6;       // 0..3
    const int ln = threadIdx.x & 63;
    const int q  = ln >> 4;
    const int n  = nt * 16 + (ln & 15);

    U16x8 H, M, L;
    #pragma unroll
    for (int j = 0; j < 8; ++j) {
        const int k = kb * 32 + q * 8 + j;
        unsigned short h, m, l;
        split3(Wg[(size_t)k * NE + n], h, m, l);
        H.v[j] = (short)h; M.v[j] = (short)m; L.v[j] = (short)l;
    }
    uint4* base = Wf + (size_t)kb * 12 * 64 + ln;
    base[(0 * 4 + nt) * 64] = H.u;
    base[(1 * 4 + nt) * 64] = M.u;
    base[(2 * 4 + nt) * 64] = L.u;
}

// GEMM: block = 8 waves x 32 tokens = 256 tokens x 64 experts; KSPLIT=4
// (pinned). Grid = 256 = 1 block/CU, 2 waves/SIMD, one pass.
//
// A-path (rounds 0-6 pinned at ~900 GB/s HBM: 128 B/row-visit page thrash):
// staged per SUPER-STEP (4 K-steps) into LDS As with 512-B contiguous
// per-row bursts (16 global_load_lds/wave, each 2 rows x 512 B).
//
// Bank-conflict fix (rule 21, both-sides-or-neither): As rows are 512 B, so
// an unswizzled fragment read would put 16 lanes (a q-group) on one 4-bank
// group (16-way conflict). LDS dest stays LINEAR (global_load_lds
// requirement); the per-lane GLOBAL source is inverse-swizzled so LDS
// position p of row r holds logical granule p ^ (r&7); the ds_read applies
// the same XOR. 16 lanes -> 8 bank-groups = 2/bank = free (m136). Pure
// placement permutation: values bitwise identical to rounds 0/2/6.
//
// LDS: As 128 KB + Bs double-buffer 24 KB = 152 KB. ALL sync is plain
// __syncthreads() (round-6-proven). No inline asm, no counted waits.
__global__ __launch_bounds__(512, 1)
void gemm_kernel(const float* __restrict__ x, const uint4* __restrict__ Wf,
                 float* __restrict__ P)
{
    const int lane = threadIdx.x & 63;
    const int wv   = threadIdx.x >> 6;         // 0..7
    const int ks   = blockIdx.x & (KSPLIT - 1);
    const int tb   = blockIdx.x >> 2;          // 0..63
    const int t0w  = tb * 256 + wv * 32;       // this wave's first token
    const int k0   = ks * KRANGE;

    const int q    = lane >> 4;
    const int mrow = lane & 15;
    const int s7   = mrow & 7;                 // read-side XOR key

    __shared__ float As[256 * 128];            // [row][128 floats] = 128 KB
    __shared__ uint4 Bs[2][12][64];            // 24 KB, double-buffered

    const uint4* wsrc = Wf + (size_t)(k0 >> 5) * (12 * 64) + lane;

    // B-stage ownership: 12 frags over 8 waves (waves 0-3: two, 4-7: one).
    const int bcnt  = (wv < 4) ? 2 : 1;
    const int bfrag = (wv < 4) ? (2 * wv) : (4 + wv);

    // A-stage lane decomposition: instr i covers rows 2i,2i+1 of the wave's
    // 32; lane l -> row r2 = 2i + (l>>5), LDS granule position p = l&31,
    // which must hold logical granule g = p ^ (r2&7) (inverse swizzle on the
    // global source; t0w and wv*32 are multiples of 8 so r2&7 == row&7).
    const int lrow = lane >> 5;                // 0..1
    const int lgp  = lane & 31;                // LDS granule position

    f32x4 acc[2][4];
    #pragma unroll
    for (int m = 0; m < 2; ++m)
        #pragma unroll
        for (int nt = 0; nt < 4; ++nt) acc[m][nt] = (f32x4){0.f, 0.f, 0.f, 0.f};

    // ---- prologue: stage B(0) into buf 0 ----
    #pragma unroll
    for (int j = 0; j < 2; ++j)
        if (j < bcnt)
            __builtin_amdgcn_global_load_lds(
                (const AS1 void*)(wsrc + (bfrag + j) * 64),
                (AS3 void*)&Bs[0][bfrag + j][0], 16, 0, 0);

    for (int ss = 0; ss < SSTEPS; ++ss) {
        // ---- stage A(ss): 16 instrs/wave, 2 rows x 512 B contiguous each;
        //      linear LDS dest + inverse-swizzled global source ----
        #pragma unroll
        for (int i = 0; i < 16; ++i) {
            const int r2 = 2 * i + lrow;
            const int g  = lgp ^ (r2 & 7);
            __builtin_amdgcn_global_load_lds(
                (const AS1 void*)(x + (size_t)(t0w + r2) * HIDDEN
                                    + k0 + ss * 128 + g * 4),
                (AS3 void*)(As + (wv * 32 + 2 * i) * 128), 16, 0, 0);
        }

        // Drain A(ss) (+ any trailing B stage) in every wave -> As ready.
        // (WAR on As vs previous super-step's reads: covered by the last
        //  inner-loop barrier's lgkmcnt(0) drain.)
        __syncthreads();

        for (int k = 0; k < 4; ++k) {
            const int kb = ss * 4 + k;
            const int b  = kb & 1;

            // ---- B frags from shared LDS (12 x ds_read_b128) ----
            U16x8 B[12];
            #pragma unroll
            for (int i = 0; i < 12; ++i) B[i].u = Bs[b][i][lane];

            // ---- stage B(kb+1) into buf b^1 (L2-resident Wf) ----
            if (kb + 1 < KSTEPS) {
                const uint4* ws = wsrc + (size_t)(kb + 1) * (12 * 64);
                #pragma unroll
                for (int j = 0; j < 2; ++j)
                    if (j < bcnt)
                        __builtin_amdgcn_global_load_lds(
                            (const AS1 void*)(ws + (bfrag + j) * 64),
                            (AS3 void*)&Bs[b ^ 1][bfrag + j][0], 16, 0, 0);
            }

            // ---- A fragments from LDS (swizzle-matched) + compute ----
            #pragma unroll
            for (int m = 0; m < 2; ++m) {
                const float* rp = As + (size_t)(wv * 32 + 16 * m + mrow) * 128;
                const int G0 = k * 8 + q * 2;           // logical granules
                const float4 a01 = *reinterpret_cast<const float4*>(rp + ((G0    ) ^ s7) * 4);
                const float4 a23 = *reinterpret_cast<const float4*>(rp + ((G0 + 1) ^ s7) * 4);
                const float a[8] = {a01.x, a01.y, a01.z, a01.w,
                                    a23.x, a23.y, a23.z, a23.w};
                U16x8 Ah, Am, Al;
                #pragma unroll
                for (int j = 0; j < 4; ++j)
                    split2pk(a[2 * j], a[2 * j + 1], Ah.w[j], Am.w[j], Al.w[j]);

                #pragma unroll
                for (int nt = 0; nt < 4; ++nt) {
                    acc[m][nt] = __builtin_amdgcn_mfma_f32_16x16x32_bf16(Ah.v, B[0 * 4 + nt].v, acc[m][nt], 0, 0, 0);
                    acc[m][nt] = __builtin_amdgcn_mfma_f32_16x16x32_bf16(Ah.v, B[1 * 4 + nt].v, acc[m][nt], 0, 0, 0);
                    acc[m][nt] = __builtin_amdgcn_mfma_f32_16x16x32_bf16(Am.v, B[0 * 4 + nt].v, acc[m][nt], 0, 0, 0);
                    acc[m][nt] = __builtin_amdgcn_mfma_f32_16x16x32_bf16(Ah.v, B[2 * 4 + nt].v, acc[m][nt], 0, 0, 0);
                    acc[m][nt] = __builtin_amdgcn_mfma_f32_16x16x32_bf16(Am.v, B[1 * 4 + nt].v, acc[m][nt], 0, 0, 0);
                    acc[m][nt] = __builtin_amdgcn_mfma_f32_16x16x32_bf16(Al.v, B[0 * 4 + nt].v, acc[m][nt], 0, 0, 0);
                }
            }

            // End-of-step barrier: (a) my B(kb+1) stage retired -> buf b^1
            // ready for all; (b) everyone's ds_reads of Bs[b]/As retired ->
            // safe to restage next step / next super-step.
            __syncthreads();
        }
    }

    // C/D layout (m89-verified): token = t0w + m*16 + q*4 + r, expert = nt*16 + mrow
    float* prow = P + (size_t)ks * TOKENS * NE;
    #pragma unroll
    for (int m = 0; m < 2; ++m)
        #pragma unroll
        for (int nt = 0; nt < 4; ++nt)
            #pragma unroll
            for (int r = 0; r < 4; ++r)
                prow[(size_t)(t0w + m * 16 + q * 4 + r) * NE + nt * 16 + mrow] = acc[m][nt][r];
}

// Finish: sum 4 partials + verified lane=expert epilogue (4 tokens/wave).
__global__ __launch_bounds__(256, 4)
void finish_kernel(const float* __restrict__ P, const float* __restrict__ bg,
                   float* __restrict__ out, float* __restrict__ gf,
                   float* __restrict__ gm)
{
    const int lane = threadIdx.x & 63;
    const int wv   = threadIdx.x >> 6;
    const int tbase = blockIdx.x * 16 + wv * 4;

    __shared__ float fsh[NE], msh[NE];
    if (threadIdx.x < NE) { fsh[threadIdx.x] = 0.f; msh[threadIdx.x] = 0.f; }
    __syncthreads();

    const float bias = bg[lane];
    float f_acc = 0.f, m_acc = 0.f;

    for (int t = 0; t < 4; ++t) {
        const int tok = tbase + t;
        float v = bias;
        #pragma unroll
        for (int sp = 0; sp < KSPLIT; ++sp)
            v += P[((size_t)sp * TOKENS + tok) * NE + lane];

        // top-1 (value desc, index asc — matches lax.top_k tie-break)
        float v1 = v; int i1 = lane;
        #pragma unroll
        for (int off = 32; off > 0; off >>= 1) {
            const float ov = __shfl_xor(v1, off, 64);
            const int   oi = __shfl_xor(i1, off, 64);
            if (ov > v1 || (ov == v1 && oi < i1)) { v1 = ov; i1 = oi; }
        }
        // top-2
        float v2 = (lane == i1) ? -INFINITY : v; int i2 = lane;
        #pragma unroll
        for (int off = 32; off > 0; off >>= 1) {
            const float ov = __shfl_xor(v2, off, 64);
            const int   oi = __shfl_xor(i2, off, 64);
            if (ov > v2 || (ov == v2 && oi < i2)) { v2 = ov; i2 = oi; }
        }

        // full 64-way softmax (for m_i)
        const float e = expf(v - v1);
        float sm = e;
        #pragma unroll
        for (int off = 32; off > 0; off >>= 1) sm += __shfl_xor(sm, off, 64);
        m_acc += e / sm;
        f_acc += ((lane == i1) ? 1.f : 0.f) + ((lane == i2) ? 1.f : 0.f);

        // softmax over top-2 (max v1 already subtracted)
        const float p  = expf(v2 - v1);
        const float s0 = 1.f / (1.f + p);
        const float s1 = p / (1.f + p);

        if (lane == 0) {
            out[IDX_OFF + tok * 2 + 0] = (float)i1;
            out[IDX_OFF + tok * 2 + 1] = (float)i2;
        } else if (lane == 1) {
            out[SC_OFF + tok * 2 + 0] = s0;
            out[SC_OFF + tok * 2 + 1] = s1;
        }
        out[MASK_OFF + (size_t)tok * 2 * NE + lane]      = (lane == i1) ? 1.f : 0.f;
        out[MASK_OFF + (size_t)tok * 2 * NE + NE + lane] = (lane == i2) ? 1.f : 0.f;
    }

    atomicAdd(&fsh[lane], f_acc);
    atomicAdd(&msh[lane], m_acc);
    __syncthreads();
    if (threadIdx.x < NE) {
        atomicAdd(&gf[threadIdx.x], fsh[threadIdx.x]);
        atomicAdd(&gm[threadIdx.x], msh[threadIdx.x]);
    }
}

// aux_loss = 0.01 * sum(f_i * m_i) / 64
__global__ void aux_kernel(const float* __restrict__ gf,
                           const float* __restrict__ gm,
                           float* __restrict__ out)
{
    const int lane = threadIdx.x;
    const float f = gf[lane] / (float)(TOKENS * 2);
    const float m = gm[lane] / (float)TOKENS;
    float p = f * m;
    #pragma unroll
    for (int off = 32; off > 0; off >>= 1) p += __shfl_xor(p, off, 64);
    if (lane == 0) out[AUX_OFF] = 0.01f * p / (float)NE;
}

extern "C" void kernel_launch(void* const* d_in, const int* in_sizes, int n_in,
                              void* d_out, int out_size, void* d_ws, size_t ws_size,
                              hipStream_t stream)
{
    const float* x  = (const float*)d_in[0];
    const float* Wg = (const float*)d_in[1];
    const float* bg = (const float*)d_in[2];
    float* out = (float*)d_out;

    uint4* Wf = (uint4*)d_ws;                         // 1.5 MB split-W frags
    float* P  = (float*)d_ws + (size_t)WF_UINT4 * 4;  // 16.8 MB partials
    float* gf = P + P_FLOATS;
    float* gm = gf + NE;

    hipMemsetAsync(gf, 0, 2 * NE * sizeof(float), stream);

    prep_w<<<KB_TOTAL, 256, 0, stream>>>(Wg, Wf);
    gemm_kernel<<<(TOKENS / 256) * KSPLIT, 512, 0, stream>>>(x, Wf, P);
    finish_kernel<<<TOKENS / 16, 256, 0, stream>>>(P, bg, out, gf, gm);
    aux_kernel<<<1, 64, 0, stream>>>(gf, gm, out);
}